// Round 17
// baseline (116.916 us; speedup 1.0000x reference)
//
#include <hip/hip_runtime.h>
#include <hip/hip_bf16.h>

// Shapes: B=2, C=256, H=W=24 (HW=576), G=16, Cg=16, GRID=25, AC=6400, Mg=400
// Inputs fp32, output fp32.
// ws layout: h1b (bf16 ushort)[4,718,592] | pooled f32[204,800] | aff f32[512]
// Harness floor: d_ws fill ~41 us + ~25 us aux. Controllable: k12+k3+k4.
// LESSON (R9): per-lane arrays indexed ONLY by compile-time constants.
// LESSON (R11/R12): don't shard phase1 (m-split) or the inner GEMM (<6 MFMA).
// LESSON (R14): non-pow2 LDS pitches; no per-element rsqrt.
// LESSON (R16): barriers alone aren't the stall; k12 is VALU-issue bound at
//   2 waves/SIMD -> this round: 40 KB LDS (4 blk/CU) AND only 4 barriers,
//   W2 preloaded to registers pre-barrier so restage exposes no latency.

typedef __attribute__((ext_vector_type(8))) short short8;
typedef __attribute__((ext_vector_type(4))) float f32x4;

static __device__ __forceinline__ unsigned short f2bf(float x) {
    unsigned u = __float_as_uint(x);
    unsigned r = (u + 0x7fffu + ((u >> 16) & 1u)) >> 16;   // RNE
    return (unsigned short)r;
}

// LDS overlay (40,160 B -> granule 40,448 -> 4 blocks/CU):
//  phase A: xs [row27][col26][ci p24] @0 (33,696) | wA [kk5][co16][k p40] @33,696 (6,400)
//  phase B: hsb [s576][j p20] @0 (23,040) | wlb [m400][j16] @23,040 (12,800)
//           bias2 @35,840 (1,600) | pacc @37,440 (1,600) | zpad @39,040 (16)
//           (zpad aliases wA -> re-zeroed between barriers #2 and #3)
//  bias1 [16] @40,096 (64)  (persistent: staging + phase 1)
#define WA_OFF   33696
#define WLB_OFF  23040
#define B2_OFF   35840
#define PACC_OFF 37440
#define ZP_OFF   39040
#define BB1_OFF  40096
#define SMEM_BYTES 40160

__global__ __launch_bounds__(256) void k12_fused(
    const float* __restrict__ xin,
    const float* __restrict__ W1,
    const float* __restrict__ g1, const float* __restrict__ b1,
    const float* __restrict__ m1, const float* __restrict__ v1,
    const float* __restrict__ W2,
    const float* __restrict__ g2, const float* __restrict__ b2,
    const float* __restrict__ m2, const float* __restrict__ v2,
    unsigned short* __restrict__ h1b,
    float* __restrict__ pooled)
{
    __shared__ __align__(16) char smem[SMEM_BYTES];
    short* xs    = (short*)smem;
    short* wAp   = (short*)(smem + WA_OFF);
    short* hsb   = (short*)smem;
    short* wlb   = (short*)(smem + WLB_OFF);
    float* bias2 = (float*)(smem + B2_OFF);
    float* pacc  = (float*)(smem + PACC_OFF);
    float* bias1 = (float*)(smem + BB1_OFF);

    int bid = blockIdx.x;                      // i*32 + b*16 + g
    int i = bid >> 5, b = (bid >> 4) & 1, g = bid & 15;
    int t = threadIdx.x;

    // ---- W2 preload into registers (global latency overlapped w/ staging) ----
    float4 w2r[2][4];
    float  bsc[2];                             // folded bias2 for m = t, t+256
    {
#pragma unroll
        for (int it = 0; it < 2; it++) {
            int m = t + it*256;
            bool act = (m < 400);
            int o = i*6400 + g*400 + (act ? m : 0);
            float s2 = g2[o] * rsqrtf(v2[o] + 1e-5f);
            bsc[it] = b2[o] - m2[o] * s2;
            const float4* wr = (const float4*)&W2[o*16];
#pragma unroll
            for (int q = 0; q < 4; q++) {
                float4 wv = wr[q];
                wv.x *= s2; wv.y *= s2; wv.z *= s2; wv.w *= s2;
                w2r[it][q] = wv;
            }
        }
    }

    // ---- staging: halo-zero xs, interior xs, wA, bias1 ----
    if (t < 16) {
        int c = i*256 + g*16 + t;
        float sc = g1[c] * rsqrtf(v1[c] + 1e-5f);
        bias1[t] = b1[c] - m1[c] * sc;
    }
    {
        int* xz = (int*)xs;
        for (int idx = t; idx < 1512; idx += 256) {
            int c = idx / 12, j = idx - (idx / 12) * 12;
            int row, col;
            if (c < 26)      { row = 0;  col = c; }
            else if (c < 52) { row = 25; col = c - 26; }
            else if (c < 78) { row = 26; col = c - 52; }
            else { int k = c - 78; row = 1 + (k >> 1); col = (k & 1) ? 25 : 0; }
            xz[(row*26 + col)*12 + j] = 0;
        }
    }
    {
        const float* xb = &xin[(b*256 + g*16)*576];
        for (int idx = t; idx < 9216; idx += 256) {
            int ci = idx / 576; int s = idx - ci*576;
            int y = s / 24; int x = s - y*24;
            xs[((y+1)*26 + (x+1))*24 + ci] = (short)f2bf(xb[idx]);
        }
    }
    {
        const float* wb = &W1[(i*256 + g*16)*144];    // [co][ci][9]
        for (int idx = t; idx < 2560; idx += 256) {
            int kk = idx >> 9, rem = idx & 511, co = rem >> 5, k = rem & 31;
            int tap = 2*kk + (k >> 4), ci = k & 15;
            int c = i*256 + g*16 + co;
            float sc = g1[c] * rsqrtf(v1[c] + 1e-5f);
            float val = (tap < 9) ? wb[co*144 + ci*9 + tap] * sc : 0.f;
            wAp[(kk*16 + co)*40 + k] = (short)f2bf(val);
        }
    }
    __syncthreads();                           // #1: staging complete

    int l = t & 63, w = t >> 6;                // 4 waves, 9 pixel-tiles each
    int quad = l >> 4, rc = l & 15;

    // ---- phase 1: D(16co x 576px) = W1'(16x144)*im2col + bias1 ----
    f32x4 dreg[9];
    {
        int ci0 = (quad & 1) * 8;
        short8 afr[5];
#pragma unroll
        for (int kk = 0; kk < 5; kk++)
            afr[kk] = *(const short8*)&wAp[(kk*16 + rc)*40 + quad*8];
        f32x4 cb1 = *(const f32x4*)&bias1[quad*4];

        const int offE[5] = {0, 48, 648, 1248, 1296};     // taps 0,2,4,6,8
        const int offO[5] = {24, 624, 672, 1272, 1872};   // taps 1,3,5,7,9(A=0)
        int off[5];
#pragma unroll
        for (int kk = 0; kk < 5; kk++) off[kk] = (quad >= 2) ? offO[kk] : offE[kk];

#pragma unroll
        for (int tt = 0; tt < 9; tt++) {
            int s = (w*9 + tt)*16 + rc;
            int y = s / 24; int x = s - y*24;
            int base = (y*26 + x)*24 + ci0;
            f32x4 acc = cb1;
#pragma unroll
            for (int kk = 0; kk < 5; kk++) {
                short8 bf = *(const short8*)&xs[base + off[kk]];
                acc = __builtin_amdgcn_mfma_f32_16x16x32_bf16(afr[kk], bf, acc, 0, 0, 0);
            }
#pragma unroll
            for (int r = 0; r < 4; r++) acc[r] = fmaxf(acc[r], 0.f);
            dreg[tt] = acc;
        }
    }
    __syncthreads();                           // #2: xs/wA reads done

    // ---- hsb (own tiles) + h1b global; wlb/bias2 from registers; pacc/zpad ----
    {
        unsigned short* hout = &h1b[((i*2 + b)*256 + g*16)*576];
#pragma unroll
        for (int tt = 0; tt < 9; tt++) {
            int s = (w*9 + tt)*16 + rc;
            f32x4 acc = dreg[tt];
            unsigned short e0 = f2bf(acc[0]), e1 = f2bf(acc[1]);
            unsigned short e2 = f2bf(acc[2]), e3 = f2bf(acc[3]);
            uint2 pk = {(unsigned)e0 | ((unsigned)e1 << 16),
                        (unsigned)e2 | ((unsigned)e3 << 16)};
            *(uint2*)&hsb[s*20 + quad*4] = pk;
            hout[(quad*4 + 0)*576 + s] = e0;
            hout[(quad*4 + 1)*576 + s] = e1;
            hout[(quad*4 + 2)*576 + s] = e2;
            hout[(quad*4 + 3)*576 + s] = e3;
        }
    }
#pragma unroll
    for (int it = 0; it < 2; it++) {
        int m = t + it*256;
        if (m < 400) {
            pacc[m]  = 0.f;
            bias2[m] = bsc[it];
#pragma unroll
            for (int q = 0; q < 4; q++) {
                float4 wv = w2r[it][q];
                wlb[m*16 + q*4 + 0] = (short)f2bf(wv.x);
                wlb[m*16 + q*4 + 1] = (short)f2bf(wv.y);
                wlb[m*16 + q*4 + 2] = (short)f2bf(wv.z);
                wlb[m*16 + q*4 + 3] = (short)f2bf(wv.w);
            }
        }
    }
    if (t < 4) ((int*)(smem + ZP_OFF))[t] = 0;
    __syncthreads();                           // #3: wlb/bias2/pacc ready

    // ---- phase 2 (transposed, registered A): D2[s,m] = h(s,j)*W2'(j,m)+be[m]
    {
        int q8 = (quad & 1) * 8;               // j-offset quads 0/1; 2/3 read zpad
        short8 af2[9];
#pragma unroll
        for (int u = 0; u < 9; u++) {
            int boff = (l < 32) ? ((((w*9 + u)*16 + rc)*20 + q8)*2) : ZP_OFF;
            af2[u] = *(const short8*)(smem + boff);
        }
        for (int mt = 0; mt < 25; mt++) {
            int m0 = mt*16;
            int woff = (l < 32) ? (WLB_OFF + ((m0 + rc)*16 + q8)*2) : ZP_OFF;
            short8 wf = *(const short8*)(smem + woff);
            float be = bias2[m0 + rc];
            f32x4 cb = {be, be, be, be};       // bias per column m

            f32x4 accv = {0.f, 0.f, 0.f, 0.f};
#pragma unroll
            for (int u = 0; u < 9; u++) {
                f32x4 d = __builtin_amdgcn_mfma_f32_16x16x32_bf16(af2[u], wf, cb, 0, 0, 0);
#pragma unroll
                for (int r = 0; r < 4; r++)
                    accv[r] += fmaxf(d[r], 0.f);
            }
            float a = (accv[0] + accv[1]) + (accv[2] + accv[3]);
            a += __shfl_xor(a, 16);            // sum 4 quads = 16 rows per tile
            a += __shfl_xor(a, 32);
            if (l < 16)
                atomicAdd(&pacc[m0 + l], a);   // ds_add_f32, 4 waves per addr
        }
    }
    __syncthreads();                           // #4: pacc complete

    const float inv = 1.f / 676.f;             // 26x26 pool incl. 100 border px
    for (int m = t; m < 400; m += 256) {
        float be = bias2[m];
        pooled[(i*2+b)*6400 + g*400 + m] =
            (pacc[m] + 100.f * fmaxf(be, 0.f)) * inv;
    }
}

// k3: aff per (i,b) — 32 blocks only
__global__ __launch_bounds__(256) void k3_aff(const float* __restrict__ pooled,
                                              float* __restrict__ aff)
{
    __shared__ float th[400];
    __shared__ float parts[256];
    int bid = blockIdx.x;           // i*2 + b
    int i = bid >> 1;
    int t = threadIdx.x;
    const float* pb = &pooled[bid*6400];
    for (int idx = t; idx < 400; idx += 256) th[idx] = pb[i*400 + idx];
    __syncthreads();
    int l = t >> 4, p = t & 15;
    float sum = 0.f;
    const float* pl = &pb[l*400];
    for (int m = p*25; m < p*25 + 25; m++) sum = fmaf(th[m], pl[m], sum);
    parts[t] = sum;
    __syncthreads();
    if (t < 16) {
        float s = 0.f;
        for (int pp = 0; pp < 16; pp++) s += parts[t*16 + pp];
        aff[bid*16 + t] = s * (1.f/16.f);
    }
}

// k4: output contraction; quad-pixel loads (uint2 = 4 bf16 px), float4 stores,
// single balanced iteration (t < 144).
__global__ __launch_bounds__(256) void k4_out(const unsigned short* __restrict__ h1b,
                                              const float* __restrict__ aff,
                                              float* __restrict__ out)
{
    __shared__ float a0[16], a1[16];
    int bid = blockIdx.x;           // i*32 + q*16 + cg
    int i = bid >> 5, q = (bid >> 4) & 1, cg = bid & 15;
    int t = threadIdx.x;
    if (t < 16) a0[t] = aff[(i*2+0)*16 + t];
    else if (t < 32) a1[t-16] = aff[(i*2+1)*16 + (t-16)];
    __syncthreads();
    if (t >= 144) return;
    const unsigned short* hb = &h1b[((i*2+q)*256 + cg)*576];
    int ch = i*32 + q*16 + cg;
    int s = t*4;                    // 144 quads cover 576 px
    float c00=0.f,c01=0.f,c02=0.f,c03=0.f;
    float c10=0.f,c11=0.f,c12=0.f,c13=0.f;
#pragma unroll
    for (int k = 0; k < 16; k++) {
        uint2 hv = *(const uint2*)&hb[k*9216 + s];
        float p0 = __uint_as_float(hv.x << 16);
        float p1 = __uint_as_float(hv.x & 0xffff0000u);
        float p2 = __uint_as_float(hv.y << 16);
        float p3 = __uint_as_float(hv.y & 0xffff0000u);
        float va = a0[k], vb = a1[k];
        c00 = fmaf(va, p0, c00); c01 = fmaf(va, p1, c01);
        c02 = fmaf(va, p2, c02); c03 = fmaf(va, p3, c03);
        c10 = fmaf(vb, p0, c10); c11 = fmaf(vb, p1, c11);
        c12 = fmaf(vb, p2, c12); c13 = fmaf(vb, p3, c13);
    }
    float4 o0 = {c00, c01, c02, c03};
    float4 o1 = {c10, c11, c12, c13};
    *(float4*)&out[ch*576 + s]         = o0;
    *(float4*)&out[(512 + ch)*576 + s] = o1;
}

extern "C" void kernel_launch(void* const* d_in, const int* in_sizes, int n_in,
                              void* d_out, int out_size, void* d_ws, size_t ws_size,
                              hipStream_t stream)
{
    const float* x  = (const float*)d_in[0];
    const float* W1 = (const float*)d_in[1];
    const float* g1 = (const float*)d_in[2];
    const float* b1 = (const float*)d_in[3];
    const float* m1 = (const float*)d_in[4];
    const float* v1 = (const float*)d_in[5];
    const float* W2 = (const float*)d_in[6];
    const float* g2 = (const float*)d_in[7];
    const float* b2 = (const float*)d_in[8];
    const float* m2 = (const float*)d_in[9];
    const float* v2 = (const float*)d_in[10];

    unsigned short* h1b = (unsigned short*)d_ws;          // 4,718,592 ushorts
    float* pooled = (float*)(h1b + 16*2*256*576);         // 204,800 floats
    float* aff    = pooled + 204800;                      // 512 floats

    float* out = (float*)d_out;

    hipLaunchKernelGGL(k12_fused, dim3(512), dim3(256), 0, stream,
                       x, W1, g1, b1, m1, v1, W2, g2, b2, m2, v2, h1b, pooled);
    hipLaunchKernelGGL(k3_aff,    dim3(32),  dim3(256), 0, stream,
                       pooled, aff);
    hipLaunchKernelGGL(k4_out,    dim3(512), dim3(256), 0, stream,
                       h1b, aff, out);
}

// Round 18
// 111.752 us; speedup vs baseline: 1.0462x; 1.0462x over previous
//
#include <hip/hip_runtime.h>
#include <hip/hip_bf16.h>

// Shapes: B=2, C=256, H=W=24 (HW=576), G=16, Cg=16, GRID=25, AC=6400, Mg=400
// Inputs fp32, output fp32.
// ws layout: h1b (bf16 ushort)[4,718,592] | pooled f32[204,800] | aff f32[512]
// Harness floor: d_ws fill ~41 us + ~28 us aux dispatches. Controllable: k12+k3+k4.
// LESSON (R9): per-lane arrays indexed ONLY by compile-time constants; the
//   512-thread config was never cleanly tested (R9 confounded by spill).
// LESSON (R11/R12): no work duplication; >=4 MFMA per phase-2 strip.
// LESSON (R14): non-pow2 LDS pitches; no per-element rsqrt.
// LESSON (R16/R17): barriers and LDS size are NOT the stall; occupancy was
//   grid-capped at 2 waves/SIMD -> this round: 512-thr blocks, 4 waves/SIMD.

typedef __attribute__((ext_vector_type(8))) short short8;
typedef __attribute__((ext_vector_type(4))) float f32x4;

static __device__ __forceinline__ unsigned short f2bf(float x) {
    unsigned u = __float_as_uint(x);
    unsigned r = (u + 0x7fffu + ((u >> 16) & 1u)) >> 16;   // RNE
    return (unsigned short)r;
}

// LDS overlay (40,160 B; 2 blocks/CU = 80.3 KB of 160 KB):
//  phase A: xs [row27][col26][ci p24] @0 (33,696) | wA [kk5][co16][k p40] @33,696 (6,400)
//  phase B: hsb [s576][j p20] @0 (23,040) | wlb [m400][j16] @23,040 (12,800)
//           bias2 @35,840 (1,600) | pacc @37,440 (1,600) | zpad @39,040 (16)
//  bias1 [16] @40,096 (64)
#define WA_OFF   33696
#define WLB_OFF  23040
#define B2_OFF   35840
#define PACC_OFF 37440
#define ZP_OFF   39040
#define BB1_OFF  40096
#define SMEM_BYTES 40160

// Grid 512 x 512 threads (8 waves): tile T = tt*8 + w, tt=0..3 all waves,
// tt=4 only waves 0-3 (wave-uniform guard, compile-time array indices).
__global__ __launch_bounds__(512, 4) void k12_fused(
    const float* __restrict__ xin,
    const float* __restrict__ W1,
    const float* __restrict__ g1, const float* __restrict__ b1,
    const float* __restrict__ m1, const float* __restrict__ v1,
    const float* __restrict__ W2,
    const float* __restrict__ g2, const float* __restrict__ b2,
    const float* __restrict__ m2, const float* __restrict__ v2,
    unsigned short* __restrict__ h1b,
    float* __restrict__ pooled)
{
    __shared__ __align__(16) char smem[SMEM_BYTES];
    short* xs    = (short*)smem;
    short* wAp   = (short*)(smem + WA_OFF);
    short* hsb   = (short*)smem;
    short* wlb   = (short*)(smem + WLB_OFF);
    float* bias2 = (float*)(smem + B2_OFF);
    float* pacc  = (float*)(smem + PACC_OFF);
    float* bias1 = (float*)(smem + BB1_OFF);

    int bid = blockIdx.x;                      // i*32 + b*16 + g
    int i = bid >> 5, b = (bid >> 4) & 1, g = bid & 15;
    int t = threadIdx.x;

    // ---- W2 preload into registers (1 m per thread; latency overlapped) ----
    float4 w2r[4];
    float  bsc;
    {
        bool act = (t < 400);
        int o = i*6400 + g*400 + (act ? t : 0);
        float s2 = g2[o] * rsqrtf(v2[o] + 1e-5f);
        bsc = b2[o] - m2[o] * s2;
        const float4* wr = (const float4*)&W2[o*16];
#pragma unroll
        for (int q = 0; q < 4; q++) {
            float4 wv = wr[q];
            wv.x *= s2; wv.y *= s2; wv.z *= s2; wv.w *= s2;
            w2r[q] = wv;
        }
    }

    // ---- staging: bias1, halo-zero xs, interior xs, wA ----
    if (t < 16) {
        int c = i*256 + g*16 + t;
        float sc = g1[c] * rsqrtf(v1[c] + 1e-5f);
        bias1[t] = b1[c] - m1[c] * sc;
    }
    {
        int* xz = (int*)xs;
        for (int idx = t; idx < 1512; idx += 512) {
            int c = idx / 12, j = idx - (idx / 12) * 12;
            int row, col;
            if (c < 26)      { row = 0;  col = c; }
            else if (c < 52) { row = 25; col = c - 26; }
            else if (c < 78) { row = 26; col = c - 52; }
            else { int k = c - 78; row = 1 + (k >> 1); col = (k & 1) ? 25 : 0; }
            xz[(row*26 + col)*12 + j] = 0;
        }
    }
    {
        const float* xb = &xin[(b*256 + g*16)*576];
        for (int idx = t; idx < 9216; idx += 512) {
            int ci = idx / 576; int s = idx - ci*576;
            int y = s / 24; int x = s - y*24;
            xs[((y+1)*26 + (x+1))*24 + ci] = (short)f2bf(xb[idx]);
        }
    }
    {
        const float* wb = &W1[(i*256 + g*16)*144];    // [co][ci][9]
        for (int idx = t; idx < 2560; idx += 512) {
            int kk = idx >> 9, rem = idx & 511, co = rem >> 5, k = rem & 31;
            int tap = 2*kk + (k >> 4), ci = k & 15;
            int c = i*256 + g*16 + co;
            float sc = g1[c] * rsqrtf(v1[c] + 1e-5f);
            float val = (tap < 9) ? wb[co*144 + ci*9 + tap] * sc : 0.f;
            wAp[(kk*16 + co)*40 + k] = (short)f2bf(val);
        }
    }
    __syncthreads();                           // #1: staging complete

    int l = t & 63, w = t >> 6;                // 8 waves; tiles T = tt*8 + w
    int quad = l >> 4, rc = l & 15;
    bool five = (w < 4);                       // waves 0-3 own a 5th tile

    // ---- phase 1: D(16co x 576px) = W1'(16x144)*im2col + bias1 ----
    f32x4 dreg[5];
    {
        int ci0 = (quad & 1) * 8;
        short8 afr[5];
#pragma unroll
        for (int kk = 0; kk < 5; kk++)
            afr[kk] = *(const short8*)&wAp[(kk*16 + rc)*40 + quad*8];
        f32x4 cb1 = *(const f32x4*)&bias1[quad*4];

        const int offE[5] = {0, 48, 648, 1248, 1296};     // taps 0,2,4,6,8
        const int offO[5] = {24, 624, 672, 1272, 1872};   // taps 1,3,5,7,9(A=0)
        int off[5];
#pragma unroll
        for (int kk = 0; kk < 5; kk++) off[kk] = (quad >= 2) ? offO[kk] : offE[kk];

#pragma unroll
        for (int tt = 0; tt < 5; tt++) {
            if (tt == 4 && !five) break;       // wave-uniform
            int s = (tt*8 + w)*16 + rc;
            int y = s / 24; int x = s - y*24;
            int base = (y*26 + x)*24 + ci0;
            f32x4 acc = cb1;
#pragma unroll
            for (int kk = 0; kk < 5; kk++) {
                short8 bf = *(const short8*)&xs[base + off[kk]];
                acc = __builtin_amdgcn_mfma_f32_16x16x32_bf16(afr[kk], bf, acc, 0, 0, 0);
            }
#pragma unroll
            for (int r = 0; r < 4; r++) acc[r] = fmaxf(acc[r], 0.f);
            dreg[tt] = acc;
        }
    }
    __syncthreads();                           // #2: xs/wA reads done

    // ---- hsb (own tiles) + h1b global; wlb/bias2 from registers; pacc/zpad ----
    {
        unsigned short* hout = &h1b[((i*2 + b)*256 + g*16)*576];
#pragma unroll
        for (int tt = 0; tt < 5; tt++) {
            if (tt == 4 && !five) break;
            int s = (tt*8 + w)*16 + rc;
            f32x4 acc = dreg[tt];
            unsigned short e0 = f2bf(acc[0]), e1 = f2bf(acc[1]);
            unsigned short e2 = f2bf(acc[2]), e3 = f2bf(acc[3]);
            uint2 pk = {(unsigned)e0 | ((unsigned)e1 << 16),
                        (unsigned)e2 | ((unsigned)e3 << 16)};
            *(uint2*)&hsb[s*20 + quad*4] = pk;
            hout[(quad*4 + 0)*576 + s] = e0;
            hout[(quad*4 + 1)*576 + s] = e1;
            hout[(quad*4 + 2)*576 + s] = e2;
            hout[(quad*4 + 3)*576 + s] = e3;
        }
    }
    if (t < 400) {
        pacc[t]  = 0.f;
        bias2[t] = bsc;
#pragma unroll
        for (int q = 0; q < 4; q++) {
            float4 wv = w2r[q];
            wlb[t*16 + q*4 + 0] = (short)f2bf(wv.x);
            wlb[t*16 + q*4 + 1] = (short)f2bf(wv.y);
            wlb[t*16 + q*4 + 2] = (short)f2bf(wv.z);
            wlb[t*16 + q*4 + 3] = (short)f2bf(wv.w);
        }
    }
    if (t < 4) ((int*)(smem + ZP_OFF))[t] = 0;
    __syncthreads();                           // #3: wlb/bias2/pacc ready

    // ---- phase 2 (transposed, registered A): D2[s,m] = h(s,j)*W2'(j,m)+be[m]
    {
        int q8 = (quad & 1) * 8;               // j-offset quads 0/1; 2/3 read zpad
        short8 af2[5];
#pragma unroll
        for (int u = 0; u < 5; u++) {
            bool valid = (l < 32) && (u < 4 || five);
            int boff = valid ? ((((u*8 + w)*16 + rc)*20 + q8)*2) : ZP_OFF;
            af2[u] = *(const short8*)(smem + boff);
        }
        for (int mt = 0; mt < 25; mt++) {
            int m0 = mt*16;
            int woff = (l < 32) ? (WLB_OFF + ((m0 + rc)*16 + q8)*2) : ZP_OFF;
            short8 wf = *(const short8*)(smem + woff);
            float be = bias2[m0 + rc];
            f32x4 cb = {be, be, be, be};       // bias per column m

            f32x4 accv = {0.f, 0.f, 0.f, 0.f};
#pragma unroll
            for (int u = 0; u < 4; u++) {      // tiles all waves own
                f32x4 d = __builtin_amdgcn_mfma_f32_16x16x32_bf16(af2[u], wf, cb, 0, 0, 0);
#pragma unroll
                for (int r = 0; r < 4; r++)
                    accv[r] += fmaxf(d[r], 0.f);
            }
            if (five) {                        // 5th tile, waves 0-3 only
                f32x4 d = __builtin_amdgcn_mfma_f32_16x16x32_bf16(af2[4], wf, cb, 0, 0, 0);
#pragma unroll
                for (int r = 0; r < 4; r++)
                    accv[r] += fmaxf(d[r], 0.f);
            }
            float a = (accv[0] + accv[1]) + (accv[2] + accv[3]);
            a += __shfl_xor(a, 16);            // sum 4 quads = 16 rows per tile
            a += __shfl_xor(a, 32);
            if (l < 16)
                atomicAdd(&pacc[m0 + l], a);   // ds_add_f32, 8 waves per addr
        }
    }
    __syncthreads();                           // #4: pacc complete

    const float inv = 1.f / 676.f;             // 26x26 pool incl. 100 border px
    if (t < 400) {
        float be = bias2[t];
        pooled[(i*2+b)*6400 + g*400 + t] =
            (pacc[t] + 100.f * fmaxf(be, 0.f)) * inv;
    }
}

// k3: aff per (i,b) — 32 blocks only
__global__ __launch_bounds__(256) void k3_aff(const float* __restrict__ pooled,
                                              float* __restrict__ aff)
{
    __shared__ float th[400];
    __shared__ float parts[256];
    int bid = blockIdx.x;           // i*2 + b
    int i = bid >> 1;
    int t = threadIdx.x;
    const float* pb = &pooled[bid*6400];
    for (int idx = t; idx < 400; idx += 256) th[idx] = pb[i*400 + idx];
    __syncthreads();
    int l = t >> 4, p = t & 15;
    float sum = 0.f;
    const float* pl = &pb[l*400];
    for (int m = p*25; m < p*25 + 25; m++) sum = fmaf(th[m], pl[m], sum);
    parts[t] = sum;
    __syncthreads();
    if (t < 16) {
        float s = 0.f;
        for (int pp = 0; pp < 16; pp++) s += parts[t*16 + pp];
        aff[bid*16 + t] = s * (1.f/16.f);
    }
}

// k4: output contraction; quad-pixel loads (uint2 = 4 bf16 px), float4 stores.
__global__ __launch_bounds__(256) void k4_out(const unsigned short* __restrict__ h1b,
                                              const float* __restrict__ aff,
                                              float* __restrict__ out)
{
    __shared__ float a0[16], a1[16];
    int bid = blockIdx.x;           // i*32 + q*16 + cg
    int i = bid >> 5, q = (bid >> 4) & 1, cg = bid & 15;
    int t = threadIdx.x;
    if (t < 16) a0[t] = aff[(i*2+0)*16 + t];
    else if (t < 32) a1[t-16] = aff[(i*2+1)*16 + (t-16)];
    __syncthreads();
    if (t >= 144) return;
    const unsigned short* hb = &h1b[((i*2+q)*256 + cg)*576];
    int ch = i*32 + q*16 + cg;
    int s = t*4;                    // 144 quads cover 576 px
    float c00=0.f,c01=0.f,c02=0.f,c03=0.f;
    float c10=0.f,c11=0.f,c12=0.f,c13=0.f;
#pragma unroll
    for (int k = 0; k < 16; k++) {
        uint2 hv = *(const uint2*)&hb[k*9216 + s];
        float p0 = __uint_as_float(hv.x << 16);
        float p1 = __uint_as_float(hv.x & 0xffff0000u);
        float p2 = __uint_as_float(hv.y << 16);
        float p3 = __uint_as_float(hv.y & 0xffff0000u);
        float va = a0[k], vb = a1[k];
        c00 = fmaf(va, p0, c00); c01 = fmaf(va, p1, c01);
        c02 = fmaf(va, p2, c02); c03 = fmaf(va, p3, c03);
        c10 = fmaf(vb, p0, c10); c11 = fmaf(vb, p1, c11);
        c12 = fmaf(vb, p2, c12); c13 = fmaf(vb, p3, c13);
    }
    float4 o0 = {c00, c01, c02, c03};
    float4 o1 = {c10, c11, c12, c13};
    *(float4*)&out[ch*576 + s]         = o0;
    *(float4*)&out[(512 + ch)*576 + s] = o1;
}

extern "C" void kernel_launch(void* const* d_in, const int* in_sizes, int n_in,
                              void* d_out, int out_size, void* d_ws, size_t ws_size,
                              hipStream_t stream)
{
    const float* x  = (const float*)d_in[0];
    const float* W1 = (const float*)d_in[1];
    const float* g1 = (const float*)d_in[2];
    const float* b1 = (const float*)d_in[3];
    const float* m1 = (const float*)d_in[4];
    const float* v1 = (const float*)d_in[5];
    const float* W2 = (const float*)d_in[6];
    const float* g2 = (const float*)d_in[7];
    const float* b2 = (const float*)d_in[8];
    const float* m2 = (const float*)d_in[9];
    const float* v2 = (const float*)d_in[10];

    unsigned short* h1b = (unsigned short*)d_ws;          // 4,718,592 ushorts
    float* pooled = (float*)(h1b + 16*2*256*576);         // 204,800 floats
    float* aff    = pooled + 204800;                      // 512 floats

    float* out = (float*)d_out;

    hipLaunchKernelGGL(k12_fused, dim3(512), dim3(512), 0, stream,
                       x, W1, g1, b1, m1, v1, W2, g2, b2, m2, v2, h1b, pooled);
    hipLaunchKernelGGL(k3_aff,    dim3(32),  dim3(256), 0, stream,
                       pooled, aff);
    hipLaunchKernelGGL(k4_out,    dim3(512), dim3(256), 0, stream,
                       h1b, aff, out);
}